// Round 8
// baseline (3441.103 us; speedup 1.0000x reference)
//
#include <hip/hip_runtime.h>

// ---------------- problem constants ----------------
#define Hd   256
#define Bd   16
#define Td   128
#define Ld   50
#define Vd   32000
#define G5H  1280     // 5*H

typedef __attribute__((ext_vector_type(8))) short short8v;  // 8 bf16 (4 VGPRs)
typedef __attribute__((ext_vector_type(4))) float f32x4;

__device__ __forceinline__ unsigned short f2bu(float f) {   // f32 -> bf16 bits (RNE)
  unsigned u = __float_as_uint(f);
  unsigned r = (u + 0x7fffu + ((u >> 16) & 1u)) >> 16;
  return (unsigned short)r;
}
__device__ __forceinline__ float bu2f(unsigned short b) {
  return __uint_as_float(((unsigned)b) << 16);
}
__device__ __forceinline__ float sigm(float x) { return 1.f / (1.f + __expf(-x)); }

// async global->LDS DMA, 16B/lane; LDS dest = uniform slot base + lane*16 (HW)
__device__ __forceinline__ void glds16(const unsigned short* g, char* l) {
  __builtin_amdgcn_global_load_lds(
      (const __attribute__((address_space(1))) unsigned int*)g,
      (__attribute__((address_space(3))) unsigned int*)l, 16, 0, 0);
}

// ---------------- fp32 -> bf16 conversion + MFMA fragment packing ----------------
// Plain bf16 copies: wv, w_ih, fcW. Fragment-ordered: w_hh, Z, P.
// Fragment (T,ks) = 512 shorts; lane L reads [frag*512 + L*8) =
// mat[T*16 + (L&15)][ks*32 + (L>>4)*8 .. +8).
__global__ __launch_bounds__(256) void conv_kernel(
    const float* __restrict__ wv, const float* __restrict__ w_ih,
    const float* __restrict__ fcW, const float* __restrict__ w_hh,
    const float* __restrict__ Zm, const float* __restrict__ Pm,
    unsigned short* __restrict__ wv_b, unsigned short* __restrict__ wih_b,
    unsigned short* __restrict__ fcw_b, unsigned short* __restrict__ whh_f,
    unsigned short* __restrict__ z_f, unsigned short* __restrict__ p_f)
{
  const long N0 = 2048000, N1 = N0 + 81920, N2 = N1 + 2048000;
  const long NW = 81920, NZ = 16384, NP = 16384;         // frag float4-groups
  const long N5 = N2 + NW + NZ + NP;
  for (long idx = (long)blockIdx.x * blockDim.x + threadIdx.x; idx < N5;
       idx += (long)gridDim.x * blockDim.x) {
    if (idx < N2) {                                      // plain copies
      const float* src; unsigned short* dst; long off;
      if      (idx < N0) { src = wv;   dst = wv_b;  off = idx; }
      else if (idx < N1) { src = w_ih; dst = wih_b; off = idx - N0; }
      else               { src = fcW;  dst = fcw_b; off = idx - N1; }
      float4 v = *(const float4*)(src + off * 4);
      ushort4 o;
      o.x = f2bu(v.x); o.y = f2bu(v.y); o.z = f2bu(v.z); o.w = f2bu(v.w);
      *(ushort4*)(dst + off * 4) = o;
    } else {                                             // fragment packing
      long u = idx - N2;
      const float* src; unsigned short* dst;
      if      (u < NW)      { src = w_hh; dst = whh_f; }
      else if (u < NW + NZ) { src = Zm;   dst = z_f;  u -= NW; }
      else                  { src = Pm;   dst = p_f;  u -= NW + NZ; }
      long frag = u >> 7;                 // 128 float4-groups per 512-short frag
      int g128 = (int)(u & 127);
      int lane = g128 >> 1, e0 = (g128 & 1) * 4;
      long T = frag >> 3; int ks = (int)(frag & 7);
      int lr = lane & 15, lg = lane >> 4;
      float4 v = *(const float4*)(src + (T * 16 + lr) * 256 + ks * 32 + lg * 8 + e0);
      ushort4 o;
      o.x = f2bu(v.x); o.y = f2bu(v.y); o.z = f2bu(v.z); o.w = f2bu(v.w);
      *(ushort4*)(dst + u * 4) = o;
    }
  }
}

// ---------------- per-batch prep: goal embed, ht0, goal_term, E, sumE ----------------
__global__ __launch_bounds__(256) void prep_kernel(
    const int* __restrict__ g, const int* __restrict__ ingr,
    const float* __restrict__ wv, const float* __restrict__ Ug,
    const float* __restrict__ Ym, const float* __restrict__ yb,
    float* __restrict__ E_ws, float* __restrict__ sumE,
    float* __restrict__ goal_ws, float* __restrict__ HT0)
{
  __shared__ float ge[256];
  const int b = blockIdx.x, tid = threadIdx.x;
  float s = 0.f;
  for (int i = 0; i < 8; ++i) s += wv[((size_t)g[(b << 3) + i] << 8) + tid];
  ge[tid] = s;
  __syncthreads();
  float h0 = 0.f, gt = 0.f;
  const float* ur = Ug + (tid << 8);
  const float* yr = Ym + (tid << 8);
#pragma unroll 8
  for (int k = 0; k < Hd; k += 4) {
    float4 gv = *(const float4*)(ge + k);
    float4 uv = *(const float4*)(ur + k);
    float4 yv = *(const float4*)(yr + k);
    h0 = fmaf(gv.x, uv.x, h0); h0 = fmaf(gv.y, uv.y, h0);
    h0 = fmaf(gv.z, uv.z, h0); h0 = fmaf(gv.w, uv.w, h0);
    gt = fmaf(gv.x, yv.x, gt); gt = fmaf(gv.y, yv.y, gt);
    gt = fmaf(gv.z, yv.z, gt); gt = fmaf(gv.w, yv.w, gt);
  }
  HT0[(b << 8) + tid] = h0;                    // [b][c]
  goal_ws[(b << 8) + tid] = gt + yb[tid];      // [b][c]
  float se = 0.f;
  for (int l = 0; l < Ld; ++l) {
    float v = wv[((size_t)ingr[b * Ld + l] << 8) + tid];
    E_ws[((size_t)(b * Ld + l) << 8) + tid] = v;
    se += v;
  }
  sumE[(b << 8) + tid] = se;                   // [b][k]
}

// ---------------- bf16 MFMA GEMM (128x128 tile, K=256), two epilogues ----------------
template <int MODE>
__global__ __launch_bounds__(256) void gemm_bf16(
    const unsigned short* __restrict__ A, const unsigned short* __restrict__ Bmat,
    const int* __restrict__ ridx, const float* __restrict__ bias,
    float* __restrict__ C)
{
  __shared__ unsigned short As[128 * 64];
  __shared__ unsigned short Bs[128 * 64];
  const int tid = threadIdx.x;
  const int m0 = blockIdx.x << 7, n0 = blockIdx.y << 7;
  const int wave = tid >> 6, lane = tid & 63;
  const int wm = wave >> 1, wn = wave & 1;
  const int lr = lane & 15, lg = lane >> 4;

  f32x4 acc[4][4];
#pragma unroll
  for (int i = 0; i < 4; ++i)
#pragma unroll
    for (int jj = 0; jj < 4; ++jj) acc[i][jj] = (f32x4){0.f, 0.f, 0.f, 0.f};

  const int srow = tid >> 1, shalf = tid & 1;
  const unsigned short* arow;
  {
    int gm = m0 + srow;
    if (MODE == 0) {
      int tt = gm >> 4, bb = gm & 15;
      arow = A + (size_t)ridx[bb * Td + tt] * Hd;
    } else {
      arow = A + (size_t)gm * Hd;
    }
  }
  const unsigned short* brow = Bmat + (size_t)(n0 + srow) * Hd;

  for (int k0 = 0; k0 < Hd; k0 += 64) {
#pragma unroll
    for (int c = 0; c < 4; ++c) {
      int k = shalf * 32 + c * 8;
      uint4 va = *(const uint4*)(arow + k0 + k);
      uint4 vb = *(const uint4*)(brow + k0 + k);
      int byo = (srow << 7) + ((k << 1) ^ ((srow & 7) << 4));  // XOR swizzle
      *(uint4*)((char*)As + byo) = va;
      *(uint4*)((char*)Bs + byo) = vb;
    }
    __syncthreads();
#pragma unroll
    for (int kk = 0; kk < 2; ++kk) {
      short8v af[4], bfr[4];
      const int kb = kk * 32 + lg * 8;
#pragma unroll
      for (int i = 0; i < 4; ++i) {
        int ar = wm * 64 + i * 16 + lr;
        af[i] = *(const short8v*)((const char*)As + (ar << 7) + ((kb << 1) ^ ((ar & 7) << 4)));
        int br = wn * 64 + i * 16 + lr;
        bfr[i] = *(const short8v*)((const char*)Bs + (br << 7) + ((kb << 1) ^ ((br & 7) << 4)));
      }
#pragma unroll
      for (int i = 0; i < 4; ++i)
#pragma unroll
        for (int jj = 0; jj < 4; ++jj)
          acc[i][jj] = __builtin_amdgcn_mfma_f32_16x16x32_bf16(af[i], bfr[jj], acc[i][jj], 0, 0, 0);
    }
    __syncthreads();
  }
#pragma unroll
  for (int i = 0; i < 4; ++i)
#pragma unroll
    for (int jj = 0; jj < 4; ++jj) {
      int col = n0 + wn * 64 + jj * 16 + lr;
      float bv = bias[col];
#pragma unroll
      for (int r = 0; r < 4; ++r) {
        int row = m0 + wm * 64 + i * 16 + lg * 4 + r;
        float v = acc[i][jj][r] + bv;
        if (MODE == 0) {
          int tt = row >> 4, bb = row & 15;
          C[((size_t)(bb * Td + tt)) * G5H + col] = v;   // gi[b][t][grow]
        } else {
          C[(size_t)row * Vd + col] = v;
        }
      }
    }
}

// ---------------- recurrence v8: one WG per batch, zero cross-WG sync ----------------
// 896 threads (14 waves). Waves 0-9: stream full w_hh (640 frags) from L2 via
// global_load_lds rings (4 slots, distance-3, counted vmcnt) + MFMA vs ht.
// Waves 10-13 (atid=tid-640): gates, P-stream->h_proj, attention, Z-stream->zd.
// gh(t+1) streams DURING attn(t) — weight stream hides under attention.
#define RNN_SMEM 103232
__global__ __launch_bounds__(896, 1) void rnn_kernel(
    const unsigned short* __restrict__ whh_f, const unsigned short* __restrict__ z_f,
    const unsigned short* __restrict__ p_f, const float* __restrict__ b_hh,
    const float* __restrict__ Sm, const float* __restrict__ z_bias,
    const float* __restrict__ gi, const float* __restrict__ goal_ws,
    const float* __restrict__ E_ws, const float* __restrict__ sumE,
    const float* __restrict__ HT0,
    unsigned short* __restrict__ out_all, float* __restrict__ d_out)
{
  extern __shared__ char smem[];
  char* ring_w = smem;                                        // 10 waves * 4096
  char* ring_a = smem + 40960;                                // 4 waves * 4096
  unsigned short* E_lds = (unsigned short*)(smem + 57344);    // 50*264
  float* gh    = (float*)(smem + 83744);                      // 1280
  float* zd    = (float*)(smem + 88864);                      // 256
  float* hp    = (float*)(smem + 89888);                      // 256
  float* hrow  = (float*)(smem + 90912);                      // 256
  unsigned short* ht_hi = (unsigned short*)(smem + 91936);    // 256
  unsigned short* ht_lo = (unsigned short*)(smem + 92448);    // 256
  unsigned short* tp_hi = (unsigned short*)(smem + 92960);    // 256
  unsigned short* tp_lo = (unsigned short*)(smem + 93472);    // 256
  float* se    = (float*)(smem + 93984);                      // 256
  float* gl    = (float*)(smem + 95008);                      // 256
  float* zb    = (float*)(smem + 96032);                      // 256
  float* bh    = (float*)(smem + 97056);                      // 1280
  float* a_l   = (float*)(smem + 102176);                     // 64
  float* d_l   = (float*)(smem + 102432);                     // 64
  float* an_l  = (float*)(smem + 102688);                     // 64
  float* au_l  = (float*)(smem + 102944);                     // 64
  float* sd    = (float*)(smem + 103200);                     // 4
  float* refl  = (float*)(smem + 103216);                     // 4

  const int b = blockIdx.x;
  const int tid = threadIdx.x;
  const int lane = tid & 63, wid = tid >> 6;
  const int lr = lane & 15, lg = lane >> 4;
  const int atid = tid - 640;                  // valid for wid >= 10

  // per-wave stream bases (only used when wid < 10 / wid >= 10 resp.)
  const unsigned short* wbase = whh_f + (((size_t)(wid < 10 ? wid : 0) * 64) << 9);
  char* ringw = ring_w + (wid < 10 ? wid : 0) * 4096;
  const int aw = (wid >= 10) ? (wid - 10) : 0;
  char* ringa = ring_a + aw * 4096;
  const unsigned short* pbase = p_f + (((size_t)aw * 32) << 9);
  const unsigned short* zbase = z_f + (((size_t)aw * 32) << 9);

  // ---- one-time LDS staging ----
  for (int idx = tid; idx < Ld * 256; idx += 896) {
    int l = idx >> 8, k = idx & 255;
    E_lds[l * 264 + k] = f2bu(E_ws[((size_t)(b * Ld + l) << 8) + k]);
  }
  for (int idx = tid; idx < 1280; idx += 896) bh[idx] = b_hh[idx];
  if (tid < 256) {
    float s0 = sumE[(b << 8) + tid];
    se[tid] = s0;
    unsigned short th = f2bu(s0);
    tp_hi[tid] = th; tp_lo[tid] = f2bu(s0 - bu2f(th));
    gl[tid] = goal_ws[(b << 8) + tid];
    zb[tid] = z_bias[tid];
    float h0 = HT0[(b << 8) + tid];
    hrow[tid] = h0;
    unsigned short hh = f2bu(h0);
    ht_hi[tid] = hh; ht_lo[tid] = f2bu(h0 - bu2f(hh));
  }
  if (tid < 64) a_l[tid] = 0.f;
  __syncthreads();

  f32x4 wacc[8];
  float g_ir = 0.f, g_iu = 0.f, g_in = 0.f, g_ig = 0.f, g_ii = 0.f;

// w-stream chunk: 16 frags, ring of 4 slots, issue distance 3, counted vmcnt.
#define WCHUNK(c)                                                              \
  {                                                                            \
    _Pragma("unroll")                                                          \
    for (int i = 0; i < 16; ++i) {                                             \
      const int f = (c) * 16 + i;                                              \
      if (f + 3 < 64)                                                          \
        glds16(wbase + (((size_t)(f + 3)) << 9) + (lane << 3),                 \
               ringw + ((f + 3) & 3) * 1024);                                  \
      if (f < 61) asm volatile("s_waitcnt vmcnt(2)" ::: "memory");             \
      else        asm volatile("s_waitcnt vmcnt(0)" ::: "memory");             \
      __builtin_amdgcn_sched_barrier(0);                                       \
      short8v av = *(const short8v*)(ringw + (f & 3) * 1024 + lane * 16);      \
      const int ks = f & 7;                                                    \
      short8v bv = (short8v){0, 0, 0, 0, 0, 0, 0, 0};                          \
      if (lr < 2)                                                              \
        bv = *(const short8v*)(((lr == 0) ? ht_hi : ht_lo) + ks * 32 + (lg << 3)); \
      wacc[f >> 3] = __builtin_amdgcn_mfma_f32_16x16x32_bf16(av, bv, wacc[f >> 3], 0, 0, 0); \
    }                                                                          \
  }

// attn-wave stream: 32 frags (4 tiles), B = (BHI,BLO), output rows into OUT.
#define ARING(FBASE, BHI, BLO, OUT)                                            \
  {                                                                            \
    f32x4 ac[4];                                                               \
    _Pragma("unroll") for (int q = 0; q < 4; ++q) ac[q] = (f32x4){0.f, 0.f, 0.f, 0.f}; \
    glds16((FBASE) + (((size_t)0) << 9) + (lane << 3), ringa + 0 * 1024);      \
    glds16((FBASE) + (((size_t)1) << 9) + (lane << 3), ringa + 1 * 1024);      \
    glds16((FBASE) + (((size_t)2) << 9) + (lane << 3), ringa + 2 * 1024);      \
    _Pragma("unroll")                                                          \
    for (int f = 0; f < 32; ++f) {                                             \
      if (f + 3 < 32)                                                          \
        glds16((FBASE) + (((size_t)(f + 3)) << 9) + (lane << 3),               \
               ringa + ((f + 3) & 3) * 1024);                                  \
      if (f < 29) asm volatile("s_waitcnt vmcnt(2)" ::: "memory");             \
      else        asm volatile("s_waitcnt vmcnt(0)" ::: "memory");             \
      __builtin_amdgcn_sched_barrier(0);                                       \
      short8v av = *(const short8v*)(ringa + (f & 3) * 1024 + lane * 16);      \
      const int ks = f & 7;                                                    \
      short8v bv = (short8v){0, 0, 0, 0, 0, 0, 0, 0};                          \
      if (lr < 2)                                                              \
        bv = *(const short8v*)(((lr == 0) ? (BHI) : (BLO)) + ks * 32 + (lg << 3)); \
      ac[f >> 3] = __builtin_amdgcn_mfma_f32_16x16x32_bf16(av, bv, ac[f >> 3], 0, 0, 0); \
    }                                                                          \
    _Pragma("unroll")                                                          \
    for (int q = 0; q < 4; ++q) {                                              \
      _Pragma("unroll")                                                        \
      for (int r = 0; r < 4; ++r) {                                            \
        float v = ac[q][r] + __shfl_xor(ac[q][r], 1);                          \
        if (lr == 0) (OUT)[(aw * 4 + q) * 16 + lg * 4 + r] = v;                \
      }                                                                        \
    }                                                                          \
  }

  // ---------- prologue: gh(0), zd(0), gi(0) ----------
  if (wid < 10) {
#pragma unroll
    for (int q = 0; q < 8; ++q) wacc[q] = (f32x4){0.f, 0.f, 0.f, 0.f};
    glds16(wbase + (((size_t)0) << 9) + (lane << 3), ringw + 0 * 1024);
    glds16(wbase + (((size_t)1) << 9) + (lane << 3), ringw + 1 * 1024);
    glds16(wbase + (((size_t)2) << 9) + (lane << 3), ringw + 2 * 1024);
    WCHUNK(0) WCHUNK(1) WCHUNK(2) WCHUNK(3)
#pragma unroll
    for (int q = 0; q < 8; ++q) {
#pragma unroll
      for (int r = 0; r < 4; ++r) {
        float v = wacc[q][r] + __shfl_xor(wacc[q][r], 1);
        if (lr == 0) gh[(wid * 8 + q) * 16 + lg * 4 + r] = v;
      }
      wacc[q] = (f32x4){0.f, 0.f, 0.f, 0.f};
    }
  } else {
    ARING(zbase, tp_hi, tp_lo, zd)
    if (atid < 256) {
      const float* gn = gi + ((size_t)(b * Td)) * G5H + atid;
      g_ir = gn[0]; g_iu = gn[256]; g_in = gn[512]; g_ig = gn[768]; g_ii = gn[1024];
    }
  }
  __syncthreads();

  for (int t = 0; t < Td; ++t) {
    const int more = (t < Td - 1);
    // ===== GATES(t) on attn waves; stream waves pre-issue first 3 frags =====
    if (wid < 10) {
      if (more) {
        glds16(wbase + (((size_t)0) << 9) + (lane << 3), ringw + 0 * 1024);
        glds16(wbase + (((size_t)1) << 9) + (lane << 3), ringw + 1 * 1024);
        glds16(wbase + (((size_t)2) << 9) + (lane << 3), ringw + 2 * 1024);
      }
    } else if (atid < 256) {
      int c = atid;
      float hr = gh[c]        + bh[c];
      float hu = gh[256 + c]  + bh[256 + c];
      float hn = gh[512 + c]  + bh[512 + c];
      float hg = gh[768 + c]  + bh[768 + c];
      float hq = gh[1024 + c] + bh[1024 + c];
      float rt = sigm(g_ir + hr), zt = sigm(g_iu + hu);
      float st_ = sigm(g_ig + hg), qt = sigm(g_ii + hq);
      float htl = tanhf(g_in + rt * hn + st_ * gl[c] + qt * (zd[c] + zb[c]));
      float prev = hrow[c];
      float h2 = htl + zt * (prev - htl);
      hrow[c] = h2;
      unsigned short hi = f2bu(h2);
      ht_hi[c] = hi; ht_lo[c] = f2bu(h2 - bu2f(hi));
    }
    __syncthreads();   // B0: ht2(t) ready
    // ===== P1: w-chunk0(t+1)  ||  P-stream->hp(t), S-dots, gi(t+1) prefetch =====
    if (wid < 10) {
      if (more) WCHUNK(0)
    } else {
      ARING(pbase, ht_hi, ht_lo, hp)
      if (atid < 192) {                              // S dots on ht2(t)
        int w = atid >> 6;
        float4 sv = *(const float4*)(Sm + (w << 8) + ((atid & 63) << 2));
        float4 hv = *(const float4*)(hrow + ((atid & 63) << 2));
        float p = sv.x * hv.x + sv.y * hv.y + sv.z * hv.z + sv.w * hv.w;
        p += __shfl_xor(p, 1);  p += __shfl_xor(p, 2);  p += __shfl_xor(p, 4);
        p += __shfl_xor(p, 8);  p += __shfl_xor(p, 16); p += __shfl_xor(p, 32);
        if ((atid & 63) == 0) sd[w] = p;
      }
      if (more && atid < 256) {                      // gi(t+1) prefetch
        const float* gn = gi + ((size_t)(b * Td + t + 1)) * G5H + atid;
        g_ir = gn[0]; g_iu = gn[256]; g_in = gn[512]; g_ig = gn[768]; g_ii = gn[1024];
      }
    }
    __syncthreads();   // B1: hp, sd ready
    // ===== P2: w-chunk1  ||  E-dots + ref softmax =====
    if (wid < 10) {
      if (more) WCHUNK(1)
    } else {
      if (atid < 200) {
        int l = atid >> 2, q = atid & 3;
        const unsigned short* er = E_lds + l * 264 + (q << 6);
        const float* hq = hp + (q << 6);
        float p = 0.f;
#pragma unroll 8
        for (int i = 0; i < 32; ++i) {
          unsigned uu = *(const unsigned*)(er + 2 * i);
          float e0 = __uint_as_float(uu << 16);
          float e1 = __uint_as_float(uu & 0xffff0000u);
          p = fmaf(e0, hq[2 * i], p);
          p = fmaf(e1, hq[2 * i + 1], p);
        }
        p += __shfl_xor(p, 1); p += __shfl_xor(p, 2);
        if (q == 0) d_l[l] = p;
      } else if (atid == 208) {                      // ref = softmax(BETA*sd)
        float s0 = 5.0f * sd[0], s1 = 5.0f * sd[1], s2 = 5.0f * sd[2];
        float m = fmaxf(s0, fmaxf(s1, s2));
        float e0 = __expf(s0 - m), e1 = __expf(s1 - m), e2 = __expf(s2 - m);
        float inv = 1.f / (e0 + e1 + e2);
        refl[0] = e0 * inv; refl[1] = e1 * inv; refl[2] = e2 * inv;
      }
    }
    __syncthreads();   // B2: d_l, refl
    // ===== P3: w-chunk2  ||  alpha_n / alpha_u =====
    if (wid < 10) {
      if (more) WCHUNK(2)
    } else if (atid < 128) {
      int which = atid >> 6;
      int l = atid & 63;
      float dv;
      if (which == 0) dv = (l < Ld) ? 2.0f * (1.f - a_l[l]) * d_l[l] : -3.4e38f;
      else            dv = (l < Ld) ? 2.0f * a_l[l] * d_l[l]         : -3.4e38f;
      float m = dv;
      m = fmaxf(m, __shfl_xor(m, 1));  m = fmaxf(m, __shfl_xor(m, 2));
      m = fmaxf(m, __shfl_xor(m, 4));  m = fmaxf(m, __shfl_xor(m, 8));
      m = fmaxf(m, __shfl_xor(m, 16)); m = fmaxf(m, __shfl_xor(m, 32));
      float e = (l < Ld) ? __expf(dv - m) : 0.f;
      float ss = e;
      ss += __shfl_xor(ss, 1);  ss += __shfl_xor(ss, 2);  ss += __shfl_xor(ss, 4);
      ss += __shfl_xor(ss, 8);  ss += __shfl_xor(ss, 16); ss += __shfl_xor(ss, 32);
      float al = e / ss;
      if (which == 0) an_l[l] = al; else au_l[l] = al;
    }
    __syncthreads();   // B3: alphas
    // ===== P4: w-chunk3  ||  F: c_n, c_u, out, tmp(t+1) =====
    if (wid < 10) {
      if (more) WCHUNK(3)
    } else if (atid < 256) {
      int k = atid;
      float accn = 0.f, accu = 0.f, acct = 0.f;
#pragma unroll 10
      for (int l = 0; l < Ld; ++l) {
        float e = bu2f(E_lds[l * 264 + k]);
        accn = fmaf(an_l[l], e, accn);
        accu = fmaf(au_l[l], e, accu);
        acct = fmaf(a_l[l], e, acct);              // a BEFORE this step's update
      }
      float outv = refl[0] * hp[k] + refl[1] * accn + refl[2] * accu;
      out_all[(((b << 7) + t) << 8) + k] = f2bu(outv);
      float tn = se[k] - acct;                     // tmp(t+1)
      unsigned short th = f2bu(tn);
      tp_hi[k] = th; tp_lo[k] = f2bu(tn - bu2f(th));
      if (t == Td - 1) {
        d_out[(size_t)65536000 + (b << 8) + k] = hrow[k];
        for (int l = 0; l < Ld; ++l) {             // E_new = (1-a_pre)*E
          size_t o = ((size_t)(b * Ld + l) << 8) + k;
          d_out[(size_t)65540896 + o] = (1.f - a_l[l]) * E_ws[o];
        }
      }
    }
    __syncthreads();   // B4: tp(t+1)
    // ===== P5: gh(t+1) writeout  ||  Z-stream->zd(t+1), a-update =====
    if (wid < 10) {
      if (more) {
#pragma unroll
        for (int q = 0; q < 8; ++q) {
#pragma unroll
          for (int r = 0; r < 4; ++r) {
            float v = wacc[q][r] + __shfl_xor(wacc[q][r], 1);
            if (lr == 0) gh[(wid * 8 + q) * 16 + lg * 4 + r] = v;
          }
          wacc[q] = (f32x4){0.f, 0.f, 0.f, 0.f};
        }
      }
    } else {
      if (atid < Ld) {                             // a update
        float na = a_l[atid] + refl[1] * an_l[atid];
        a_l[atid] = na;
        if (t == Td - 1) d_out[(size_t)65540096 + b * Ld + atid] = na;
      }
      if (more) ARING(zbase, tp_hi, tp_lo, zd)
    }
    __syncthreads();   // B5 -> gates(t+1)
  }
#undef WCHUNK
#undef ARING
}

// ---------------- host launcher ----------------
extern "C" void kernel_launch(void* const* d_in, const int* in_sizes, int n_in,
                              void* d_out, int out_size, void* d_ws, size_t ws_size,
                              hipStream_t stream)
{
  const int*   recipe = (const int*)d_in[0];
  const int*   g      = (const int*)d_in[1];
  const int*   ingr   = (const int*)d_in[2];
  const float* wv     = (const float*)d_in[3];
  const float* w_ih   = (const float*)d_in[4];
  const float* w_hh   = (const float*)d_in[5];
  const float* b_ih   = (const float*)d_in[6];
  const float* b_hh   = (const float*)d_in[7];
  const float* Z      = (const float*)d_in[8];
  const float* Y      = (const float*)d_in[9];
  const float* Ug     = (const float*)d_in[10];
  const float* z_bias = (const float*)d_in[11];
  const float* y_bias = (const float*)d_in[12];
  const float* S      = (const float*)d_in[13];
  const float* P      = (const float*)d_in[14];
  const float* fcW    = (const float*)d_in[15];
  const float* fcb    = (const float*)d_in[16];
  float* out = (float*)d_out;
  char* ws = (char*)d_ws;

  size_t off = 0;
  unsigned short* wv_b     = (unsigned short*)(ws + off);  off += 16384000;
  unsigned short* wih_b    = (unsigned short*)(ws + off);  off += 655360;
  unsigned short* fcw_b    = (unsigned short*)(ws + off);  off += 16384000;
  unsigned short* whh_f    = (unsigned short*)(ws + off);  off += 655360;
  unsigned short* z_f      = (unsigned short*)(ws + off);  off += 131072;
  unsigned short* p_f      = (unsigned short*)(ws + off);  off += 131072;
  float* gi_ws             = (float*)(ws + off);           off += 10485760;
  float* E_ws              = (float*)(ws + off);           off += 819200;
  float* sumE              = (float*)(ws + off);           off += 16384;
  float* goal_ws           = (float*)(ws + off);           off += 16384;
  float* HT0               = (float*)(ws + off);           off += 16384;
  unsigned short* out_all  = (unsigned short*)(ws + off);  off += 1048576;

  conv_kernel<<<4096, 256, 0, stream>>>(wv, w_ih, fcW, w_hh, Z, P,
                                        wv_b, wih_b, fcw_b, whh_f, z_f, p_f);
  prep_kernel<<<16, 256, 0, stream>>>(g, ingr, wv, Ug, Y, y_bias,
                                      E_ws, sumE, goal_ws, HT0);
  gemm_bf16<0><<<dim3(16, 10), 256, 0, stream>>>(wv_b, wih_b, recipe, b_ih, gi_ws);
  hipFuncSetAttribute((const void*)rnn_kernel,
                      hipFuncAttributeMaxDynamicSharedMemorySize, RNN_SMEM);
  rnn_kernel<<<16, 896, RNN_SMEM, stream>>>(whh_f, z_f, p_f, b_hh, S, z_bias,
                                            gi_ws, goal_ws, E_ws, sumE, HT0,
                                            out_all, out);
  gemm_bf16<1><<<dim3(16, 250), 256, 0, stream>>>(out_all, fcw_b, nullptr, fcb, out);
}

// Round 10
// 1638.047 us; speedup vs baseline: 2.1007x; 2.1007x over previous
//
#include <hip/hip_runtime.h>

// ---------------- problem constants ----------------
#define Hd   256
#define Bd   16
#define Td   128
#define Ld   50
#define Vd   32000
#define G5H  1280     // 5*H

typedef __attribute__((ext_vector_type(8))) short short8v;  // 8 bf16 (4 VGPRs)
typedef __attribute__((ext_vector_type(4))) float f32x4;

__device__ __forceinline__ unsigned short f2bu(float f) {   // f32 -> bf16 bits (RNE)
  unsigned u = __float_as_uint(f);
  unsigned r = (u + 0x7fffu + ((u >> 16) & 1u)) >> 16;
  return (unsigned short)r;
}
__device__ __forceinline__ float bu2f(unsigned short b) {
  return __uint_as_float(((unsigned)b) << 16);
}
__device__ __forceinline__ float sigm(float x) { return 1.f / (1.f + __expf(-x)); }

// agent-scope (MALL) relaxed ops — PROVEN-correct cross-XCD path (rounds 2/7)
__device__ __forceinline__ void st_devu(unsigned* p, unsigned v) {
  __hip_atomic_store(p, v, __ATOMIC_RELAXED, __HIP_MEMORY_SCOPE_AGENT);
}
__device__ __forceinline__ unsigned ld_devu(const unsigned* p) {
  return __hip_atomic_load((unsigned*)p, __ATOMIC_RELAXED, __HIP_MEMORY_SCOPE_AGENT);
}
__device__ __forceinline__ void st_devd(double* p, double v) {
  __hip_atomic_store(p, v, __ATOMIC_RELAXED, __HIP_MEMORY_SCOPE_AGENT);
}
__device__ __forceinline__ double ld_devd(const double* p) {
  return __hip_atomic_load((double*)p, __ATOMIC_RELAXED, __HIP_MEMORY_SCOPE_AGENT);
}
__device__ __forceinline__ double pk2(float a, float b) {
  union { double d; float2 f; } u; u.f = make_float2(a, b); return u.d;
}

// ---------------- fp32 -> bf16 conversion + MFMA fragment packing ----------------
__global__ __launch_bounds__(256) void conv_kernel(
    const float* __restrict__ wv, const float* __restrict__ w_ih,
    const float* __restrict__ fcW, const float* __restrict__ w_hh,
    const float* __restrict__ Zm, const float* __restrict__ Pm,
    unsigned short* __restrict__ wv_b, unsigned short* __restrict__ wih_b,
    unsigned short* __restrict__ fcw_b, unsigned short* __restrict__ whh_f,
    unsigned short* __restrict__ z_f, unsigned short* __restrict__ p_f)
{
  const long N0 = 2048000, N1 = N0 + 81920, N2 = N1 + 2048000;
  const long NW = 81920, NZ = 16384, NP = 16384;         // frag float4-groups
  const long N5 = N2 + NW + NZ + NP;
  for (long idx = (long)blockIdx.x * blockDim.x + threadIdx.x; idx < N5;
       idx += (long)gridDim.x * blockDim.x) {
    if (idx < N2) {                                      // plain copies
      const float* src; unsigned short* dst; long off;
      if      (idx < N0) { src = wv;   dst = wv_b;  off = idx; }
      else if (idx < N1) { src = w_ih; dst = wih_b; off = idx - N0; }
      else               { src = fcW;  dst = fcw_b; off = idx - N1; }
      float4 v = *(const float4*)(src + off * 4);
      ushort4 o;
      o.x = f2bu(v.x); o.y = f2bu(v.y); o.z = f2bu(v.z); o.w = f2bu(v.w);
      *(ushort4*)(dst + off * 4) = o;
    } else {                                             // fragment packing
      long u = idx - N2;
      const float* src; unsigned short* dst;
      if      (u < NW)      { src = w_hh; dst = whh_f; }
      else if (u < NW + NZ) { src = Zm;   dst = z_f;  u -= NW; }
      else                  { src = Pm;   dst = p_f;  u -= NW + NZ; }
      long frag = u >> 7;                 // 128 float4-groups per 512-short frag
      int g128 = (int)(u & 127);
      int lane = g128 >> 1, e0 = (g128 & 1) * 4;
      long T = frag >> 3; int ks = (int)(frag & 7);
      int lr = lane & 15, lg = lane >> 4;
      float4 v = *(const float4*)(src + (T * 16 + lr) * 256 + ks * 32 + lg * 8 + e0);
      ushort4 o;
      o.x = f2bu(v.x); o.y = f2bu(v.y); o.z = f2bu(v.z); o.w = f2bu(v.w);
      *(ushort4*)(dst + u * 4) = o;
    }
  }
}

// ---------------- per-batch prep: goal embed, ht0, goal_term, E, sumE ----------------
__global__ __launch_bounds__(256) void prep_kernel(
    const int* __restrict__ g, const int* __restrict__ ingr,
    const float* __restrict__ wv, const float* __restrict__ Ug,
    const float* __restrict__ Ym, const float* __restrict__ yb,
    float* __restrict__ E_ws, float* __restrict__ sumE,
    float* __restrict__ goal_ws, float* __restrict__ HT0)
{
  __shared__ float ge[256];
  const int b = blockIdx.x, tid = threadIdx.x;
  float s = 0.f;
  for (int i = 0; i < 8; ++i) s += wv[((size_t)g[(b << 3) + i] << 8) + tid];
  ge[tid] = s;
  __syncthreads();
  float h0 = 0.f, gt = 0.f;
  const float* ur = Ug + (tid << 8);
  const float* yr = Ym + (tid << 8);
#pragma unroll 8
  for (int k = 0; k < Hd; k += 4) {
    float4 gv = *(const float4*)(ge + k);
    float4 uv = *(const float4*)(ur + k);
    float4 yv = *(const float4*)(yr + k);
    h0 = fmaf(gv.x, uv.x, h0); h0 = fmaf(gv.y, uv.y, h0);
    h0 = fmaf(gv.z, uv.z, h0); h0 = fmaf(gv.w, uv.w, h0);
    gt = fmaf(gv.x, yv.x, gt); gt = fmaf(gv.y, yv.y, gt);
    gt = fmaf(gv.z, yv.z, gt); gt = fmaf(gv.w, yv.w, gt);
  }
  HT0[(b << 8) + tid] = h0;                    // [b][c]
  goal_ws[(b << 8) + tid] = gt + yb[tid];      // [b][c]
  float se = 0.f;
  for (int l = 0; l < Ld; ++l) {
    float v = wv[((size_t)ingr[b * Ld + l] << 8) + tid];
    E_ws[((size_t)(b * Ld + l) << 8) + tid] = v;
    se += v;
  }
  sumE[(b << 8) + tid] = se;                   // [b][k]
}

// ---------------- bf16 MFMA GEMM (128x128 tile, K=256), two epilogues ----------------
template <int MODE>
__global__ __launch_bounds__(256) void gemm_bf16(
    const unsigned short* __restrict__ A, const unsigned short* __restrict__ Bmat,
    const int* __restrict__ ridx, const float* __restrict__ bias,
    float* __restrict__ C)
{
  __shared__ unsigned short As[128 * 64];
  __shared__ unsigned short Bs[128 * 64];
  const int tid = threadIdx.x;
  const int m0 = blockIdx.x << 7, n0 = blockIdx.y << 7;
  const int wave = tid >> 6, lane = tid & 63;
  const int wm = wave >> 1, wn = wave & 1;
  const int lr = lane & 15, lg = lane >> 4;

  f32x4 acc[4][4];
#pragma unroll
  for (int i = 0; i < 4; ++i)
#pragma unroll
    for (int jj = 0; jj < 4; ++jj) acc[i][jj] = (f32x4){0.f, 0.f, 0.f, 0.f};

  const int srow = tid >> 1, shalf = tid & 1;
  const unsigned short* arow;
  {
    int gm = m0 + srow;
    if (MODE == 0) {
      int tt = gm >> 4, bb = gm & 15;
      arow = A + (size_t)ridx[bb * Td + tt] * Hd;
    } else {
      arow = A + (size_t)gm * Hd;
    }
  }
  const unsigned short* brow = Bmat + (size_t)(n0 + srow) * Hd;

  for (int k0 = 0; k0 < Hd; k0 += 64) {
#pragma unroll
    for (int c = 0; c < 4; ++c) {
      int k = shalf * 32 + c * 8;
      uint4 va = *(const uint4*)(arow + k0 + k);
      uint4 vb = *(const uint4*)(brow + k0 + k);
      int byo = (srow << 7) + ((k << 1) ^ ((srow & 7) << 4));  // XOR swizzle
      *(uint4*)((char*)As + byo) = va;
      *(uint4*)((char*)Bs + byo) = vb;
    }
    __syncthreads();
#pragma unroll
    for (int kk = 0; kk < 2; ++kk) {
      short8v af[4], bfr[4];
      const int kb = kk * 32 + lg * 8;
#pragma unroll
      for (int i = 0; i < 4; ++i) {
        int ar = wm * 64 + i * 16 + lr;
        af[i] = *(const short8v*)((const char*)As + (ar << 7) + ((kb << 1) ^ ((ar & 7) << 4)));
        int br = wn * 64 + i * 16 + lr;
        bfr[i] = *(const short8v*)((const char*)Bs + (br << 7) + ((kb << 1) ^ ((br & 7) << 4)));
      }
#pragma unroll
      for (int i = 0; i < 4; ++i)
#pragma unroll
        for (int jj = 0; jj < 4; ++jj)
          acc[i][jj] = __builtin_amdgcn_mfma_f32_16x16x32_bf16(af[i], bfr[jj], acc[i][jj], 0, 0, 0);
    }
    __syncthreads();
  }
#pragma unroll
  for (int i = 0; i < 4; ++i)
#pragma unroll
    for (int jj = 0; jj < 4; ++jj) {
      int col = n0 + wn * 64 + jj * 16 + lr;
      float bv = bias[col];
#pragma unroll
      for (int r = 0; r < 4; ++r) {
        int row = m0 + wm * 64 + i * 16 + lg * 4 + r;
        float v = acc[i][jj][r] + bv;
        if (MODE == 0) {
          int tt = row >> 4, bb = row & 15;
          C[((size_t)(bb * Td + tt)) * G5H + col] = v;   // gi[b][t][grow]
        } else {
          C[(size_t)row * Vd + col] = v;
        }
      }
    }
}

// ---------------- recurrence v10: round-7 base + single-flag deferred-H rendezvous ----------------
// 8 WGs per batch (b = idx>>3, j = idx&7), agent-scope (MALL) exchange only.
// Per step: A1 (gh+zd MFMA) -> A2 (gates, publish ht2 slice + sd partials) ->
// A3 (hp partials, publish) -> drain -> ONE flag -> ONE poll -> gather hp+sd ->
// attention D2/E/F/G -> gather ht2 (flag already confirmed: no second poll).
// Payload packed as 64-bit relaxed agent atomics (halves MALL transactions).
#define RNN_SMEM 149440
__global__ __launch_bounds__(256, 1) void rnn_kernel(
    const unsigned short* __restrict__ whh_f, const unsigned short* __restrict__ z_f,
    const unsigned short* __restrict__ p_f, const float* __restrict__ b_hh,
    const float* __restrict__ Sm, const float* __restrict__ z_bias,
    const float* __restrict__ gi, const float* __restrict__ goal_ws,
    const float* __restrict__ E_ws, const float* __restrict__ sumE,
    const float* __restrict__ HT0,
    unsigned short* __restrict__ out_all, float* __restrict__ d_out,
    float* __restrict__ XBH, float* __restrict__ XBP, unsigned* __restrict__ FL)
{
  extern __shared__ char smem[];
  unsigned short* w_lds = (unsigned short*)(smem);            // 10 tiles*8ks*512
  unsigned short* z_lds = (unsigned short*)(smem + 81920);    // 2*8*512
  unsigned short* p_lds = (unsigned short*)(smem + 98304);    // 16*512 (ks=j)
  unsigned short* E_lds = (unsigned short*)(smem + 114688);   // 50*264
  float* hrow  = (float*)(smem + 141088);   // 256 fp32 ht (current, full)
  float* hp    = (float*)(smem + 142112);   // 256 h_proj (full, summed)
  float* gh    = (float*)(smem + 143136);   // 160 (g*32+cl)
  float* zd    = (float*)(smem + 143776);   // 32
  float* se    = (float*)(smem + 143904);   // 256
  float* gl    = (float*)(smem + 144928);   // 32 (goal_term slice)
  float* bh    = (float*)(smem + 145056);   // 160
  float* zb    = (float*)(smem + 145696);   // 32
  float* a_l   = (float*)(smem + 145824);   // 64
  float* d_l   = (float*)(smem + 146080);   // 64
  float* an_l  = (float*)(smem + 146336);   // 64
  float* au_l  = (float*)(smem + 146592);   // 64
  float* sd    = (float*)(smem + 146848);   // 4
  float* refl  = (float*)(smem + 146864);   // 4
  unsigned short* ht_hi = (unsigned short*)(smem + 146880);   // 256
  unsigned short* ht_lo = (unsigned short*)(smem + 147392);   // 256
  unsigned short* tp_hi = (unsigned short*)(smem + 147904);   // 256
  unsigned short* tp_lo = (unsigned short*)(smem + 148416);   // 256
  unsigned short* hs_hi = (unsigned short*)(smem + 148928);   // 32 (ht2 slice)
  unsigned short* hs_lo = (unsigned short*)(smem + 148992);   // 32
  float* Sl    = (float*)(smem + 149056);   // 96 (S slice [3][32])

  const int b  = blockIdx.x >> 3;
  const int j  = blockIdx.x & 7;
  const int hc0 = j << 5;
  const int tid = threadIdx.x;
  const int lane = tid & 63, wid = tid >> 6;
  const int lr = lane & 15, lg = lane >> 4;
  unsigned* FLb = FL + (b << 5);             // 128B per batch: one line

  // ---- one-time staging ----
  for (int idx = tid; idx < 5120; idx += 256) {        // w_hh slice (uint4 units)
    int f = idx >> 6, e = idx & 63;
    int q = f >> 3, ks = f & 7;
    int T = (q >> 1) * 16 + 2 * j + (q & 1);
    *(uint4*)(w_lds + ((size_t)f << 9) + e * 8) =
        *(const uint4*)(whh_f + (((size_t)T * 8 + ks) << 9) + e * 8);
  }
  for (int idx = tid; idx < 1024; idx += 256) {        // Z slice
    int f = idx >> 6, e = idx & 63;
    int q = f >> 3, ks = f & 7;
    int T = 2 * j + q;
    *(uint4*)(z_lds + ((size_t)f << 9) + e * 8) =
        *(const uint4*)(z_f + (((size_t)T * 8 + ks) << 9) + e * 8);
  }
  for (int idx = tid; idx < 1024; idx += 256) {        // P column-slice (ks=j)
    int f = idx >> 6, e = idx & 63;
    *(uint4*)(p_lds + ((size_t)f << 9) + e * 8) =
        *(const uint4*)(p_f + (((size_t)f * 8 + j) << 9) + e * 8);
  }
  for (int idx = tid; idx < Ld * 256; idx += 256) {    // E bf16
    int l = idx >> 8, k = idx & 255;
    E_lds[l * 264 + k] = f2bu(E_ws[((size_t)(b * Ld + l) << 8) + k]);
  }
  if (tid < 160) bh[tid] = b_hh[((tid >> 5) << 8) + hc0 + (tid & 31)];
  if (tid < 96) Sl[tid] = Sm[((tid >> 5) << 8) + hc0 + (tid & 31)];
  if (tid < 32) {
    gl[tid] = goal_ws[(b << 8) + hc0 + tid];
    zb[tid] = z_bias[hc0 + tid];
  }
  if (tid < 256) {
    float s0 = sumE[(b << 8) + tid];
    se[tid] = s0;
    unsigned short hi = f2bu(s0);
    tp_hi[tid] = hi; tp_lo[tid] = f2bu(s0 - bu2f(hi));
    float h0 = HT0[(b << 8) + tid];
    hrow[tid] = h0;
    unsigned short hh = f2bu(h0);
    ht_hi[tid] = hh; ht_lo[tid] = f2bu(h0 - bu2f(hh));
  }
  if (tid < 64) a_l[tid] = 0.f;
  __syncthreads();

  for (int t = 0; t < Td; ++t) {
    const int par = t & 1;
    double* htpub = (double*)XBH + ((size_t)((par * 16 + b) * 8 + j)) * 16;
    const double* htr = (const double*)XBH + ((size_t)((par * 16 + b) * 8)) * 16;
    double* hppub = (double*)XBP + ((size_t)((par * 16 + b) * 8 + j)) * 132;
    const double* hpr = (const double*)XBP + ((size_t)((par * 16 + b) * 8)) * 132;
    // ---- gi prefetch (tid<32), hides under A1 ----
    float g_ir = 0.f, g_iu = 0.f, g_in = 0.f, g_ig = 0.f, g_ii = 0.f;
    if (tid < 32) {
      const float* gib = gi + ((size_t)(b * Td + t)) * G5H + hc0 + tid;
      g_ir = gib[0];    g_iu = gib[256];  g_in = gib[512];
      g_ig = gib[768];  g_ii = gib[1024];
    }
    // ========== A1: gh (10 tiles) + zd (2 tiles), 3 tiles/wave ==========
#pragma unroll
    for (int ti = 0; ti < 3; ++ti) {
      int q = wid * 3 + ti;
      const unsigned short* base = (q < 10) ? (w_lds + ((size_t)(q * 8) << 9))
                                            : (z_lds + ((size_t)((q - 10) * 8) << 9));
      const unsigned short* shi = (q < 10) ? ht_hi : tp_hi;
      const unsigned short* slo = (q < 10) ? ht_lo : tp_lo;
      f32x4 acc = (f32x4){0.f, 0.f, 0.f, 0.f};
#pragma unroll
      for (int ks = 0; ks < 8; ++ks) {
        short8v av = *(const short8v*)(base + ((size_t)ks << 9) + (lane << 3));
        short8v bv = (short8v){0, 0, 0, 0, 0, 0, 0, 0};
        if (lr < 2)
          bv = *(const short8v*)((lr == 0 ? shi : slo) + ks * 32 + (lg << 3));
        acc = __builtin_amdgcn_mfma_f32_16x16x32_bf16(av, bv, acc, 0, 0, 0);
      }
#pragma unroll
      for (int r = 0; r < 4; ++r) {
        float v = acc[r] + __shfl_xor(acc[r], 1);        // col0(hi)+col1(lo)
        if (lr == 0) {
          int row = q * 16 + lg * 4 + r;
          if (q < 10) gh[row] = v; else zd[row - 160] = v;
        }
      }
    }
    __syncthreads();
    // ========== A2: gates -> ht2 slice + sd partials; publish (packed doubles) ==========
    if (tid < 32) {
      int cl = tid;
      float hr = gh[cl]       + bh[cl];
      float hu = gh[32 + cl]  + bh[32 + cl];
      float hn = gh[64 + cl]  + bh[64 + cl];
      float hg = gh[96 + cl]  + bh[96 + cl];
      float hq = gh[128 + cl] + bh[128 + cl];
      float rt = sigm(g_ir + hr), zt = sigm(g_iu + hu);
      float st = sigm(g_ig + hg), qt = sigm(g_ii + hq);
      float htl = tanhf(g_in + rt * hn + st * gl[cl] + qt * (zd[cl] + zb[cl]));
      float prev = hrow[hc0 + cl];
      float h2 = htl + zt * (prev - htl);
      unsigned short hi = f2bu(h2);
      hs_hi[cl] = hi; hs_lo[cl] = f2bu(h2 - bu2f(hi));
      // sd partials over this 32-col slice (3 dots, 32-lane reduce)
      float p0 = Sl[cl] * h2, p1 = Sl[32 + cl] * h2, p2 = Sl[64 + cl] * h2;
      p0 += __shfl_xor(p0, 1);  p0 += __shfl_xor(p0, 2);  p0 += __shfl_xor(p0, 4);
      p0 += __shfl_xor(p0, 8);  p0 += __shfl_xor(p0, 16);
      p1 += __shfl_xor(p1, 1);  p1 += __shfl_xor(p1, 2);  p1 += __shfl_xor(p1, 4);
      p1 += __shfl_xor(p1, 8);  p1 += __shfl_xor(p1, 16);
      p2 += __shfl_xor(p2, 1);  p2 += __shfl_xor(p2, 2);  p2 += __shfl_xor(p2, 4);
      p2 += __shfl_xor(p2, 8);  p2 += __shfl_xor(p2, 16);
      float h2o = __shfl_xor(h2, 1);
      if (!(cl & 1)) st_devd(htpub + (cl >> 1), pk2(h2, h2o));   // ht2 slice pairs
      if (cl == 0) {
        st_devd(hppub + 128, pk2(p0, p1));                       // sd partials
        st_devd(hppub + 129, pk2(p2, 0.f));
      }
    }
    __syncthreads();
    // ========== A3: h_proj partial (16 tiles, K=32) -> publish packed ==========
#pragma unroll
    for (int ti = 0; ti < 4; ++ti) {
      int q = wid * 4 + ti;
      short8v av = *(const short8v*)(p_lds + ((size_t)q << 9) + (lane << 3));
      short8v bv = (short8v){0, 0, 0, 0, 0, 0, 0, 0};
      if (lr < 2)
        bv = *(const short8v*)((lr == 0 ? hs_hi : hs_lo) + (lg << 3));
      f32x4 acc = (f32x4){0.f, 0.f, 0.f, 0.f};
      acc = __builtin_amdgcn_mfma_f32_16x16x32_bf16(av, bv, acc, 0, 0, 0);
      float vv[4];
#pragma unroll
      for (int r = 0; r < 4; ++r) vv[r] = acc[r] + __shfl_xor(acc[r], 1);
      if (lr == 0) {
        int row = q * 16 + lg * 4;
        st_devd(hppub + (row >> 1), pk2(vv[0], vv[1]));
        st_devd(hppub + (row >> 1) + 1, pk2(vv[2], vv[3]));
      }
    }
    // ---- drain all payload stores, then ONE flag ----
    asm volatile("s_waitcnt vmcnt(0)" ::: "memory");
    __syncthreads();
    if (tid == 0) st_devu(FLb + j, (unsigned)(t + 1));
    // ---- single poll (covers BOTH ht and hp payloads) ----
    if (tid < 64) {
      unsigned tgt = (unsigned)(t + 1);
      int guard = 0;
      while (1) {
        unsigned v = (lane < 8) ? ld_devu(FLb + lane) : tgt;
        if (__all((int)(v >= tgt))) break;
        __builtin_amdgcn_s_sleep(1);
        if (++guard > (1 << 20)) break;
      }
    }
    __syncthreads();
    // ========== GATH-P: hp full (j-ascending order) + sd sums ==========
    if (tid < 128) {
      union { double d; float2 f; } u0, u1, u2, u3, u4, u5, u6, u7;
      u0.d = ld_devd(hpr + 0 * 132 + tid);
      u1.d = ld_devd(hpr + 1 * 132 + tid);
      u2.d = ld_devd(hpr + 2 * 132 + tid);
      u3.d = ld_devd(hpr + 3 * 132 + tid);
      u4.d = ld_devd(hpr + 4 * 132 + tid);
      u5.d = ld_devd(hpr + 5 * 132 + tid);
      u6.d = ld_devd(hpr + 6 * 132 + tid);
      u7.d = ld_devd(hpr + 7 * 132 + tid);
      float slo = ((((((u0.f.x + u1.f.x) + u2.f.x) + u3.f.x) + u4.f.x) + u5.f.x)
                   + u6.f.x) + u7.f.x;
      float shi = ((((((u0.f.y + u1.f.y) + u2.f.y) + u3.f.y) + u4.f.y) + u5.f.y)
                   + u6.f.y) + u7.f.y;
      hp[2 * tid] = slo;
      hp[2 * tid + 1] = shi;
    } else if (tid < 131) {
      int w = tid - 128;
      float s = 0.f;
#pragma unroll
      for (int js = 0; js < 8; ++js) {
        union { double d; float2 f; } u;
        u.d = ld_devd(hpr + js * 132 + 128 + (w >> 1));
        s += (w & 1) ? u.f.y : u.f.x;
      }
      sd[w] = s;
    }
    __syncthreads();
    // ========== D2: E-dots + ref softmax ==========
    if (tid < 200) {
      int l = tid >> 2, q = tid & 3;
      const unsigned short* er = E_lds + l * 264 + (q << 6);
      const float* hq = hp + (q << 6);
      float p = 0.f;
#pragma unroll 8
      for (int i = 0; i < 32; ++i) {
        unsigned uu = *(const unsigned*)(er + 2 * i);
        float e0 = __uint_as_float(uu << 16);
        float e1 = __uint_as_float(uu & 0xffff0000u);
        p = fmaf(e0, hq[2 * i], p);
        p = fmaf(e1, hq[2 * i + 1], p);
      }
      p += __shfl_xor(p, 1); p += __shfl_xor(p, 2);
      if (q == 0) d_l[l] = p;
    } else if (tid == 224) {                        // ref = softmax(BETA*sd)
      float s0 = 5.0f * sd[0], s1 = 5.0f * sd[1], s2 = 5.0f * sd[2];
      float m = fmaxf(s0, fmaxf(s1, s2));
      float e0 = __expf(s0 - m), e1 = __expf(s1 - m), e2 = __expf(s2 - m);
      float inv = 1.f / (e0 + e1 + e2);
      refl[0] = e0 * inv; refl[1] = e1 * inv; refl[2] = e2 * inv;
    }
    __syncthreads();
    // ========== E: alpha_n / alpha_u ==========
    if (tid < 128) {
      int which = tid >> 6;
      int l = tid & 63;
      float dv;
      if (which == 0) dv = (l < Ld) ? 2.0f * (1.f - a_l[l]) * d_l[l] : -3.4e38f;
      else            dv = (l < Ld) ? 2.0f * a_l[l] * d_l[l]         : -3.4e38f;
      float m = dv;
      m = fmaxf(m, __shfl_xor(m, 1));  m = fmaxf(m, __shfl_xor(m, 2));
      m = fmaxf(m, __shfl_xor(m, 4));  m = fmaxf(m, __shfl_xor(m, 8));
      m = fmaxf(m, __shfl_xor(m, 16)); m = fmaxf(m, __shfl_xor(m, 32));
      float e = (l < Ld) ? __expf(dv - m) : 0.f;
      float ss = e;
      ss += __shfl_xor(ss, 1);  ss += __shfl_xor(ss, 2);  ss += __shfl_xor(ss, 4);
      ss += __shfl_xor(ss, 8);  ss += __shfl_xor(ss, 16); ss += __shfl_xor(ss, 32);
      float al = e / ss;
      if (which == 0) an_l[l] = al; else au_l[l] = al;
    }
    __syncthreads();
    // ========== F: c_n, c_u, out, tmp(t+1)  (replicated; WG0 stores) ==========
    {
      int k = tid;
      float accn = 0.f, accu = 0.f, acct = 0.f;
#pragma unroll 10
      for (int l = 0; l < Ld; ++l) {
        float e = bu2f(E_lds[l * 264 + k]);
        accn = fmaf(an_l[l], e, accn);
        accu = fmaf(au_l[l], e, accu);
        acct = fmaf(a_l[l], e, acct);              // a BEFORE this step's update
      }
      float outv = refl[0] * hp[k] + refl[1] * accn + refl[2] * accu;
      float tn = se[k] - acct;                     // tmp(t+1) = sum((1-a)*E)
      unsigned short th = f2bu(tn);
      tp_hi[k] = th; tp_lo[k] = f2bu(tn - bu2f(th));
      if (j == 0) {
        out_all[(((b << 7) + t) << 8) + k] = f2bu(outv);
        if (t == Td - 1) {
          for (int l = 0; l < Ld; ++l) {           // E_new = (1-a_pre)*E
            size_t o = ((size_t)(b * Ld + l) << 8) + k;
            d_out[(size_t)65540896 + o] = (1.f - a_l[l]) * E_ws[o];
          }
        }
      }
    }
    __syncthreads();
    // ========== G: a update ==========
    if (tid < Ld) {
      float na = a_l[tid] + refl[1] * an_l[tid];
      a_l[tid] = na;
      if (t == Td - 1 && j == 0) d_out[(size_t)65540096 + b * Ld + tid] = na;
    }
    __syncthreads();
    // ========== GATH-H: full ht2 (flag already confirmed -> no poll) ==========
    if (tid < 128) {
      union { double d; float2 f; } u;
      u.d = ld_devd(htr + (tid >> 4) * 16 + (tid & 15));
      int c0 = 2 * tid;
      float a0 = u.f.x, a1 = u.f.y;
      hrow[c0] = a0; hrow[c0 + 1] = a1;
      unsigned short h0 = f2bu(a0), h1 = f2bu(a1);
      ht_hi[c0] = h0;     ht_lo[c0] = f2bu(a0 - bu2f(h0));
      ht_hi[c0 + 1] = h1; ht_lo[c0 + 1] = f2bu(a1 - bu2f(h1));
      if (t == Td - 1 && j == 0) {
        d_out[(size_t)65536000 + (b << 8) + c0] = a0;
        d_out[(size_t)65536000 + (b << 8) + c0 + 1] = a1;
      }
    }
    __syncthreads();
  }
}

// ---------------- host launcher ----------------
extern "C" void kernel_launch(void* const* d_in, const int* in_sizes, int n_in,
                              void* d_out, int out_size, void* d_ws, size_t ws_size,
                              hipStream_t stream)
{
  const int*   recipe = (const int*)d_in[0];
  const int*   g      = (const int*)d_in[1];
  const int*   ingr   = (const int*)d_in[2];
  const float* wv     = (const float*)d_in[3];
  const float* w_ih   = (const float*)d_in[4];
  const float* w_hh   = (const float*)d_in[5];
  const float* b_ih   = (const float*)d_in[6];
  const float* b_hh   = (const float*)d_in[7];
  const float* Z      = (const float*)d_in[8];
  const float* Y      = (const float*)d_in[9];
  const float* Ug     = (const float*)d_in[10];
  const float* z_bias = (const float*)d_in[11];
  const float* y_bias = (const float*)d_in[12];
  const float* S      = (const float*)d_in[13];
  const float* P      = (const float*)d_in[14];
  const float* fcW    = (const float*)d_in[15];
  const float* fcb    = (const float*)d_in[16];
  float* out = (float*)d_out;
  char* ws = (char*)d_ws;

  size_t off = 0;
  unsigned* FL             = (unsigned*)(ws + off);        off += 2048;
  float* XBH               = (float*)(ws + off);           off += 32768;
  float* XBP               = (float*)(ws + off);           off += 270336;
  unsigned short* wv_b     = (unsigned short*)(ws + off);  off += 16384000;
  unsigned short* wih_b    = (unsigned short*)(ws + off);  off += 655360;
  unsigned short* fcw_b    = (unsigned short*)(ws + off);  off += 16384000;
  unsigned short* whh_f    = (unsigned short*)(ws + off);  off += 655360;
  unsigned short* z_f      = (unsigned short*)(ws + off);  off += 131072;
  unsigned short* p_f      = (unsigned short*)(ws + off);  off += 131072;
  float* gi_ws             = (float*)(ws + off);           off += 10485760;
  float* E_ws              = (float*)(ws + off);           off += 819200;
  float* sumE              = (float*)(ws + off);           off += 16384;
  float* goal_ws           = (float*)(ws + off);           off += 16384;
  float* HT0               = (float*)(ws + off);           off += 16384;
  unsigned short* out_all  = (unsigned short*)(ws + off);  off += 1048576;

  hipMemsetAsync(FL, 0, 2048, stream);
  conv_kernel<<<4096, 256, 0, stream>>>(wv, w_ih, fcW, w_hh, Z, P,
                                        wv_b, wih_b, fcw_b, whh_f, z_f, p_f);
  prep_kernel<<<16, 256, 0, stream>>>(g, ingr, wv, Ug, Y, y_bias,
                                      E_ws, sumE, goal_ws, HT0);
  gemm_bf16<0><<<dim3(16, 10), 256, 0, stream>>>(wv_b, wih_b, recipe, b_ih, gi_ws);
  hipFuncSetAttribute((const void*)rnn_kernel,
                      hipFuncAttributeMaxDynamicSharedMemorySize, RNN_SMEM);
  rnn_kernel<<<128, 256, RNN_SMEM, stream>>>(whh_f, z_f, p_f, b_hh, S, z_bias,
                                             gi_ws, goal_ws, E_ws, sumE, HT0,
                                             out_all, out, XBH, XBP, FL);
  gemm_bf16<1><<<dim3(16, 250), 256, 0, stream>>>(out_all, fcw_b, nullptr, fcb, out);
}